// Round 8
// baseline (285.260 us; speedup 1.0000x reference)
//
#include <hip/hip_runtime.h>

#define B_  4
#define D_  512
#define H_  8
#define DV_ 64
#define S_  2048

typedef __bf16 bf16;
typedef bf16  bf16x8 __attribute__((ext_vector_type(8)));
typedef bf16  bf16x4 __attribute__((ext_vector_type(4)));
typedef float f32x4  __attribute__((ext_vector_type(4)));

#define MFMA(a, b, c) __builtin_amdgcn_mfma_f32_16x16x32_bf16((a), (b), (c), 0, 0, 0)

// async global->LDS, 16B per lane; LDS dest is wave-uniform base + lane*16
#define GLOAD_LDS(g, l)                                                     \
    __builtin_amdgcn_global_load_lds(                                       \
        (const __attribute__((address_space(1))) void*)(g),                 \
        (__attribute__((address_space(3))) void*)(l), 16, 0, 0)

// s_waitcnt with vmcnt(n), lgkm/exp unconstrained (gfx9 encoding)
#define WAIT_VMCNT(n)                                                       \
    __builtin_amdgcn_s_waitcnt(((n) & 15) | (((n) >> 4) << 14) | (7 << 4) | (15 << 8))

// raw workgroup barrier WITHOUT the __syncthreads vmcnt(0) drain
#define RAW_BARRIER()                                                       \
    do { __asm__ volatile("" ::: "memory");                                 \
         __builtin_amdgcn_s_barrier();                                      \
         __asm__ volatile("" ::: "memory"); } while (0)

// ---------------------------------------------------------------------------
// Kernel 1: prep = transpose x (B,D,S fp32 -> B,S,D bf16)  +  pack weights
// ---------------------------------------------------------------------------
__global__ __launch_bounds__(256) void prep(
    const float* __restrict__ x, const float* __restrict__ Wq,
    const float* __restrict__ Wk, const float* __restrict__ Wv,
    const float* __restrict__ W0, bf16* __restrict__ xb, bf16* __restrict__ Wb) {
    const int bid = blockIdx.x;
    if (bid < 4096) {                            // transpose part
        __shared__ float tile[32][33];
        const int sblk = bid % 64;               // S/32
        const int dblk = (bid / 64) % 16;        // D/32
        const int b    = bid / 1024;
        const int d0 = dblk * 32, s0 = sblk * 32;
        const int tx = threadIdx.x & 31;
        const int ty = threadIdx.x >> 5;         // 0..7
        const float* xp = x + (size_t)b * D_ * S_;
#pragma unroll
        for (int i = 0; i < 32; i += 8)
            tile[ty + i][tx] = xp[(size_t)(d0 + ty + i) * S_ + s0 + tx];
        __syncthreads();
        bf16* xbp = xb + ((size_t)b * S_ + s0) * D_ + d0;
#pragma unroll
        for (int i = 0; i < 32; i += 8)
            xbp[(size_t)(ty + i) * D_ + tx] = (bf16)tile[tx][ty + i];
    } else {                                     // weight-pack part: 256 blocks
        const int f0 = ((bid - 4096) * 256 + threadIdx.x) * 16;  // 0..1048560
        const int src = f0 >> 18;                // 262144 elems per matrix
        const int off = f0 & 262143;
        const float* W = (src == 0) ? Wq : (src == 1) ? Wk : (src == 2) ? Wv : W0;
        float4 v0 = *(const float4*)&W[off];
        float4 v1 = *(const float4*)&W[off + 4];
        float4 v2 = *(const float4*)&W[off + 8];
        float4 v3 = *(const float4*)&W[off + 12];
        bf16x8 h0 = {(bf16)v0.x, (bf16)v0.y, (bf16)v0.z, (bf16)v0.w,
                     (bf16)v1.x, (bf16)v1.y, (bf16)v1.z, (bf16)v1.w};
        bf16x8 h1 = {(bf16)v2.x, (bf16)v2.y, (bf16)v2.z, (bf16)v2.w,
                     (bf16)v3.x, (bf16)v3.y, (bf16)v3.z, (bf16)v3.w};
        *(bf16x8*)&Wb[f0]     = h0;
        *(bf16x8*)&Wb[f0 + 8] = h1;
    }
}

// ---------------------------------------------------------------------------
// Kernel 2: fused QKV GEMM, m97-style core (unchanged from r7; V stored
// transposed + key-swizzled within 32-groups: key 16h+4q+r -> pos 8q+4h+r).
// ---------------------------------------------------------------------------
__global__ __launch_bounds__(256) void gemm_qkv(
    const bf16* __restrict__ A, const bf16* __restrict__ Wb,
    const float* __restrict__ bq, const float* __restrict__ bk,
    const float* __restrict__ bv,
    bf16* __restrict__ Q, bf16* __restrict__ K, bf16* __restrict__ Vt) {
    __shared__ union {
        struct { bf16 A[8192]; bf16 B[8192]; } s;
        bf16 T[128][132];                        // epilogue transpose (33792 B)
    } sm;

    const int tid = threadIdx.x;
    const int w = tid >> 6, lane = tid & 63;
    const int m16 = lane & 15, quad = lane >> 4;
    const int wr = w & 1, wc = w >> 1;

    const int nblk = blockIdx.x % 12;            // N = 1536 / 128
    const int mblk = blockIdx.x / 12;            // M = 8192 / 128
    const int m0 = mblk * 128, n0 = nblk * 128;

    f32x4 acc[4][4];
#pragma unroll
    for (int i = 0; i < 4; ++i)
#pragma unroll
        for (int j = 0; j < 4; ++j) acc[i][j] = (f32x4){0.f, 0.f, 0.f, 0.f};

    for (int k0 = 0; k0 < D_; k0 += 64) {
        __syncthreads();
#pragma unroll
        for (int i = 0; i < 4; ++i) {            // wave w stages chunks w*4..w*4+3
            const int c  = w * 4 + i;
            const int mt = c >> 1, kk = c & 1;
            const int row = mt * 16 + m16;
            const int col = k0 + kk * 32 + quad * 8;
            GLOAD_LDS(&A[(size_t)(m0 + row) * D_ + col],  &sm.s.A[(c * 64 + lane) * 8]);
            GLOAD_LDS(&Wb[(size_t)(n0 + row) * D_ + col], &sm.s.B[(c * 64 + lane) * 8]);
        }
        __syncthreads();
#pragma unroll
        for (int kk = 0; kk < 2; ++kk) {
            bf16x8 af[4], bfv[4];
#pragma unroll
            for (int t = 0; t < 4; ++t) {
                af[t]  = *(const bf16x8*)&sm.s.A[(((wr * 4 + t) * 2 + kk) * 64 + lane) * 8];
                bfv[t] = *(const bf16x8*)&sm.s.B[(((wc * 4 + t) * 2 + kk) * 64 + lane) * 8];
            }
#pragma unroll
            for (int mt = 0; mt < 4; ++mt)
#pragma unroll
                for (int nt = 0; nt < 4; ++nt)
                    acc[mt][nt] = MFMA(af[mt], bfv[nt], acc[mt][nt]);
        }
    }

    const int proj = n0 >> 9;                    // 128-tiles never straddle
    const float* bias = (proj == 0) ? bq : (proj == 1) ? bk : bv;

    if (proj == 2) {                             // V: direct swizzled store
#pragma unroll
        for (int mt = 0; mt < 4; ++mt)
#pragma unroll
            for (int nt = 0; nt < 4; ++nt) {
                const int nr = (n0 + wc * 64 + nt * 16 + m16) & 511;
                const int h = nr >> 6, e = nr & 63;
                const float bia = bias[nr];
                const int srow = m0 + wr * 64 + mt * 16 + quad * 4;
                const int b = srow >> 11, s = srow & 2047;
                const int s2 = (s & ~31) | (quad * 8 + (mt & 1) * 4);  // key swizzle
                bf16x4 hv;
#pragma unroll
                for (int r = 0; r < 4; ++r) hv[r] = (bf16)(acc[mt][nt][r] + bia);
                *(bf16x4*)&Vt[(((size_t)b * H_ + h) * DV_ + e) * S_ + s2] = hv;
            }
    } else {                                     // Q/K: LDS transpose -> bf16x8
        __syncthreads();
#pragma unroll
        for (int mt = 0; mt < 4; ++mt)
#pragma unroll
            for (int nt = 0; nt < 4; ++nt) {
                const int nloc = wc * 64 + nt * 16 + m16;
                const float bia = bias[(n0 + nloc) & 511];
#pragma unroll
                for (int r = 0; r < 4; ++r)
                    sm.T[wr * 64 + mt * 16 + quad * 4 + r][nloc] =
                        (bf16)(acc[mt][nt][r] + bia);
            }
        __syncthreads();
        const int rloc = tid >> 1, cb = (tid & 1) * 64;
        const int M = m0 + rloc, b = M >> 11, s = M & 2047;
        const int nrb = (n0 + cb) & 511;
        const int h = nrb >> 6;
        bf16* dst = ((proj == 0) ? Q : K) + (((size_t)b * H_ + h) * S_ + s) * DV_;
#pragma unroll
        for (int u = 0; u < 8; ++u)
            *(bf16x8*)&dst[u * 8] = *(const bf16x8*)&sm.T[rloc][cb + u * 8];
    }
}

// ---------------------------------------------------------------------------
// Kernel 3: flash attention v8 — q-split waves (16 q-rows/wave), block-shared
// double-buffered K/V tiles via global_load_lds, raw-barrier pipeline.
//  - Per iter: [issue tile i+1 (4 GLOADs/wave)] [compute tile i]
//    [vmcnt(0) on loads issued a full iter ago (~free)] [raw s_barrier].
//    No compiler vmcnt(0)+barrier drain anywhere in the loop.
//  - Global-source XOR column swizzle (within 128B rows; coalescing intact):
//    LDS slot c holds global chunk c^(row&7) -> all frag ds_read_b128 at the
//    8-lanes/bank-group floor.
//  - S^T QK + in-register P -> PV B-frags (v5/v6 bijection; Vt pre-swizzled
//    by gemm_qkv). l via ones-MFMA. o = 16 accums/lane only.
// ---------------------------------------------------------------------------
__global__ __launch_bounds__(256, 3) void flash_attn(
    const bf16* __restrict__ Q, const bf16* __restrict__ K, const bf16* __restrict__ Vt,
    const float* __restrict__ mask, bf16* __restrict__ heads) {
    __shared__ union {
        struct {
            bf16 Ks[2][64][64];                  // 16384 B
            bf16 Vs[2][64][64];                  // 16384 B
            float Ms[2048];                      // 8192 B
        } s;
        struct { float T[64][68]; float L[64]; } ep;
    } sm;

    const int bidx = blockIdx.x;                 // B*H*(S/64) = 1024
    const int qblk = bidx & 31;
    const int h    = (bidx >> 5) & 7;
    const int b    = bidx >> 8;
    const int q0   = qblk * 64;

    const int tid = threadIdx.x;
    const int w = tid >> 6, lane = tid & 63;
    const int m16 = lane & 15, quad = lane >> 4;

    const bf16* Qp = Q  + ((size_t)b * H_ + h) * S_ * DV_;
    const bf16* Kp = K  + ((size_t)b * H_ + h) * S_ * DV_;
    const bf16* Vp = Vt + ((size_t)b * H_ + h) * DV_ * S_;
    const float* mp = mask + (size_t)b * S_;

    // staging lane constants: row-within-8 and XOR-swizzled column chunk
    const int lrow = lane >> 3;                          // 0..7
    const int lcol = ((lane & 7) ^ lrow) * 8;            // source col elems

    // Q B-frags for this wave's 16 q-rows, pre-scaled by 1/8 (exact in bf16)
    bf16x8 qf[2];
#pragma unroll
    for (int kk = 0; kk < 2; ++kk) {
        bf16x8 v = *(const bf16x8*)&Qp[(size_t)(q0 + w * 16 + m16) * DV_ +
                                       kk * 32 + quad * 8];
#pragma unroll
        for (int i = 0; i < 8; ++i) v[i] = (bf16)((float)v[i] * 0.125f);
        qf[kk] = v;
    }

    bf16x8 ones;
#pragma unroll
    for (int i = 0; i < 8; ++i) ones[i] = (bf16)1.0f;

    f32x4 o[4];                                  // O^T[e=16et+4quad+r][q=m16]
    f32x4 lacc = (f32x4){0.f, 0.f, 0.f, 0.f};
#pragma unroll
    for (int et = 0; et < 4; ++et) o[et] = (f32x4){0.f, 0.f, 0.f, 0.f};

    // ---- prologue: mask (2 GLOADs/wave) + tile 0 (4 GLOADs/wave) ----
#pragma unroll
    for (int p = 0; p < 2; ++p) {
        const int mo = ((w * 2 + p) * 64 + lane) * 4;    // 16B of mask
        GLOAD_LDS(&mp[mo], &sm.s.Ms[mo]);
    }
#pragma unroll
    for (int p = 0; p < 2; ++p) {
        const int row = (w * 2 + p) * 8 + lrow;
        GLOAD_LDS(&Kp[(size_t)row * DV_ + lcol],
                  &sm.s.Ks[0][0][((w * 2 + p) * 64 + lane) * 8]);
        GLOAD_LDS(&Vp[(size_t)row * S_ + lcol],
                  &sm.s.Vs[0][0][((w * 2 + p) * 64 + lane) * 8]);
    }
    WAIT_VMCNT(0);
    RAW_BARRIER();

    for (int i = 0; i < 32; ++i) {
        const int t0 = i * 64;
        const int buf = i & 1;

        if (i < 31) {                            // issue tile i+1 into other buf
            const int tn = t0 + 64;
#pragma unroll
            for (int p = 0; p < 2; ++p) {
                const int row = (w * 2 + p) * 8 + lrow;
                GLOAD_LDS(&Kp[(size_t)(tn + row) * DV_ + lcol],
                          &sm.s.Ks[buf ^ 1][0][((w * 2 + p) * 64 + lane) * 8]);
                GLOAD_LDS(&Vp[(size_t)row * S_ + tn + lcol],
                          &sm.s.Vs[buf ^ 1][0][((w * 2 + p) * 64 + lane) * 8]);
            }
        }

        // K A-frags (XOR slot) + mask
        bf16x8 kf[4][2];
#pragma unroll
        for (int tt = 0; tt < 4; ++tt)
#pragma unroll
            for (int kk = 0; kk < 2; ++kk)
                kf[tt][kk] = *(const bf16x8*)&sm.s.Ks[buf][tt * 16 + m16][
                    (((kk * 4 + quad) ^ (m16 & 7)) * 8)];
        f32x4 mq[4];
#pragma unroll
        for (int tt = 0; tt < 4; ++tt)
            mq[tt] = *(const f32x4*)&sm.s.Ms[t0 + tt * 16 + quad * 4];

        // S^T: sc[tt], lane = s[t=16tt+4quad+r][q=m16]
        f32x4 sc[4];
#pragma unroll
        for (int tt = 0; tt < 4; ++tt) sc[tt] = (f32x4){0.f, 0.f, 0.f, 0.f};
#pragma unroll
        for (int kk = 0; kk < 2; ++kk)
#pragma unroll
            for (int tt = 0; tt < 4; ++tt)
                sc[tt] = MFMA(kf[tt][kk], qf[kk], sc[tt]);

        // mask + exp -> PV B-frags in-lane: pf[kh][j=4*(tt&1)+r], kh=tt>>1
        bf16x8 pf[2];
#pragma unroll
        for (int tt = 0; tt < 4; ++tt)
#pragma unroll
            for (int r = 0; r < 4; ++r) {
                const float ng = (1.0f - mq[tt][r]) * -1e30f;
                pf[tt >> 1][(tt & 1) * 4 + r] =
                    (bf16)__expf(sc[tt][r] * mq[tt][r] + ng);
            }

        // V A-frags (XOR slot) + PV + l
#pragma unroll
        for (int kh = 0; kh < 2; ++kh) {
            lacc = MFMA(ones, pf[kh], lacc);
#pragma unroll
            for (int et = 0; et < 4; ++et) {
                const bf16x8 vf = *(const bf16x8*)&sm.s.Vs[buf][et * 16 + m16][
                    (((kh * 4 + quad) ^ (m16 & 7)) * 8)];
                o[et] = MFMA(vf, pf[kh], o[et]);
            }
        }

        if (i < 31) {
            WAIT_VMCNT(0);                       // loads issued ~1 iter ago
            RAW_BARRIER();
        }
    }

    // ---- epilogue: per-block LDS transpose (union with staging) ----
    __syncthreads();                             // everyone done with staging
#pragma unroll
    for (int et = 0; et < 4; ++et)
#pragma unroll
        for (int r = 0; r < 4; ++r)
            sm.ep.T[w * 16 + m16][et * 16 + quad * 4 + r] = o[et][r];
    if (quad == 0) sm.ep.L[w * 16 + m16] = lacc[0];
    __syncthreads();

    const int ql = tid >> 2, ec = (tid & 3) * 16;
    const float l  = sm.ep.L[ql];
    const float qm = mp[q0 + ql];
    const float inv = qm / l;
    bf16x8 hv[2];
#pragma unroll
    for (int c = 0; c < 2; ++c)
#pragma unroll
        for (int i = 0; i < 8; ++i)
            hv[c][i] = (bf16)(sm.ep.T[ql][ec + c * 8 + i] * inv);
    bf16* dst = &heads[((size_t)b * S_ + q0 + ql) * D_ + h * DV_ + ec];
    *(bf16x8*)(dst)     = hv[0];
    *(bf16x8*)(dst + 8) = hv[1];
}

// ---------------------------------------------------------------------------
// Kernel 4: out projection (unchanged this round)
// ---------------------------------------------------------------------------
__global__ __launch_bounds__(256) void gemm_out(
    const bf16* __restrict__ A, const bf16* __restrict__ Wb,
    const float* __restrict__ b0, float* __restrict__ outp) {
    __shared__ bf16 Asl[8192];
    __shared__ bf16 Bsl[8192];

    const int tid = threadIdx.x;
    const int w = tid >> 6, lane = tid & 63;
    const int m16 = lane & 15, quad = lane >> 4;
    const int wr = w & 1, wc = w >> 1;

    const int nblk = blockIdx.x & 3;             // N = 512 / 128
    const int mblk = blockIdx.x >> 2;            // M = 8192 / 128
    const int m0 = mblk * 128, n0 = nblk * 128;

    f32x4 acc[4][4];
#pragma unroll
    for (int i = 0; i < 4; ++i)
#pragma unroll
        for (int j = 0; j < 4; ++j) acc[i][j] = (f32x4){0.f, 0.f, 0.f, 0.f};

    for (int k0 = 0; k0 < D_; k0 += 64) {
        __syncthreads();
#pragma unroll
        for (int i = 0; i < 4; ++i) {
            const int c  = w * 4 + i;
            const int mt = c >> 1, kk = c & 1;
            const int row = mt * 16 + m16;
            const int col = k0 + kk * 32 + quad * 8;
            GLOAD_LDS(&A[(size_t)(m0 + row) * D_ + col], &Asl[(c * 64 + lane) * 8]);
            GLOAD_LDS(&Wb[(size_t)(1536 + n0 + row) * D_ + col], &Bsl[(c * 64 + lane) * 8]);
        }
        __syncthreads();
#pragma unroll
        for (int kk = 0; kk < 2; ++kk) {
            bf16x8 af[4], bfv[4];
#pragma unroll
            for (int t = 0; t < 4; ++t) {
                af[t]  = *(const bf16x8*)&Asl[(((wr * 4 + t) * 2 + kk) * 64 + lane) * 8];
                bfv[t] = *(const bf16x8*)&Bsl[(((wc * 4 + t) * 2 + kk) * 64 + lane) * 8];
            }
#pragma unroll
            for (int mt = 0; mt < 4; ++mt)
#pragma unroll
                for (int nt = 0; nt < 4; ++nt)
                    acc[mt][nt] = MFMA(af[mt], bfv[nt], acc[mt][nt]);
        }
    }

#pragma unroll
    for (int mt = 0; mt < 4; ++mt)
#pragma unroll
        for (int nt = 0; nt < 4; ++nt) {
            const int n = n0 + wc * 64 + nt * 16 + m16;
            const float bia = b0[n];
            const int srow = m0 + wr * 64 + mt * 16 + quad * 4;
            const int b = srow >> 11, s = srow & 2047;
            float4 vv;
            vv.x = acc[mt][nt][0] + bia;
            vv.y = acc[mt][nt][1] + bia;
            vv.z = acc[mt][nt][2] + bia;
            vv.w = acc[mt][nt][3] + bia;
            *(float4*)&outp[((size_t)b * D_ + n) * S_ + s] = vv;
        }
}

// ---------------------------------------------------------------------------
extern "C" void kernel_launch(void* const* d_in, const int* in_sizes, int n_in,
                              void* d_out, int out_size, void* d_ws, size_t ws_size,
                              hipStream_t stream) {
    const float* x    = (const float*)d_in[0];
    const float* mask = (const float*)d_in[1];
    const float* Wq   = (const float*)d_in[2];
    const float* bq   = (const float*)d_in[3];
    const float* Wk   = (const float*)d_in[4];
    const float* bk   = (const float*)d_in[5];
    const float* Wv   = (const float*)d_in[6];
    const float* bv   = (const float*)d_in[7];
    const float* W0   = (const float*)d_in[8];
    const float* b0   = (const float*)d_in[9];
    float* out = (float*)d_out;

    char* ws = (char*)d_ws;
    const size_t SEG = (size_t)B_ * S_ * D_ * sizeof(bf16);   // 8 MiB
    bf16* xb    = (bf16*)(ws);            // reused as `heads` after gemm_qkv
    bf16* Qb    = (bf16*)(ws + SEG);
    bf16* Kb    = (bf16*)(ws + 2 * SEG);
    bf16* Vt    = (bf16*)(ws + 3 * SEG);
    bf16* Wb    = (bf16*)(ws + 4 * SEG);  // 2048x512 bf16 = 2 MiB
    bf16* heads = xb;

    prep<<<dim3(4096 + 256), dim3(256), 0, stream>>>(x, Wq, Wk, Wv, W0, xb, Wb);
    gemm_qkv<<<dim3(64 * 12), dim3(256), 0, stream>>>(xb, Wb, bq, bk, bv, Qb, Kb, Vt);
    flash_attn<<<dim3(B_ * H_ * (S_ / 64)), dim3(256), 0, stream>>>(Qb, Kb, Vt, mask, heads);
    gemm_out<<<dim3(64 * 4), dim3(256), 0, stream>>>(heads, Wb, b0, out);
}

// Round 9
// 242.423 us; speedup vs baseline: 1.1767x; 1.1767x over previous
//
#include <hip/hip_runtime.h>

#define B_  4
#define D_  512
#define H_  8
#define DV_ 64
#define S_  2048

typedef __bf16 bf16;
typedef bf16  bf16x8 __attribute__((ext_vector_type(8)));
typedef bf16  bf16x4 __attribute__((ext_vector_type(4)));
typedef float f32x4  __attribute__((ext_vector_type(4)));

#define MFMA(a, b, c) __builtin_amdgcn_mfma_f32_16x16x32_bf16((a), (b), (c), 0, 0, 0)

// async global->LDS, 16B per lane; LDS dest is wave-uniform base + lane*16
#define GLOAD_LDS(g, l)                                                     \
    __builtin_amdgcn_global_load_lds(                                       \
        (const __attribute__((address_space(1))) void*)(g),                 \
        (__attribute__((address_space(3))) void*)(l), 16, 0, 0)

// s_waitcnt with vmcnt(n), lgkm/exp unconstrained (gfx9 encoding)
#define WAIT_VMCNT(n)                                                       \
    __builtin_amdgcn_s_waitcnt(((n) & 15) | (((n) >> 4) << 14) | (7 << 4) | (15 << 8))

// raw workgroup barrier WITHOUT the __syncthreads vmcnt(0) drain
#define RAW_BARRIER()                                                       \
    do { __asm__ volatile("" ::: "memory");                                 \
         __builtin_amdgcn_s_barrier();                                      \
         __asm__ volatile("" ::: "memory"); } while (0)

// ---------------------------------------------------------------------------
// Kernel 1: prep = transpose x (B,D,S fp32 -> B,S,D bf16)  +  pack weights
// ---------------------------------------------------------------------------
__global__ __launch_bounds__(256) void prep(
    const float* __restrict__ x, const float* __restrict__ Wq,
    const float* __restrict__ Wk, const float* __restrict__ Wv,
    const float* __restrict__ W0, bf16* __restrict__ xb, bf16* __restrict__ Wb) {
    const int bid = blockIdx.x;
    if (bid < 4096) {                            // transpose part
        __shared__ float tile[32][33];
        const int sblk = bid % 64;               // S/32
        const int dblk = (bid / 64) % 16;        // D/32
        const int b    = bid / 1024;
        const int d0 = dblk * 32, s0 = sblk * 32;
        const int tx = threadIdx.x & 31;
        const int ty = threadIdx.x >> 5;         // 0..7
        const float* xp = x + (size_t)b * D_ * S_;
#pragma unroll
        for (int i = 0; i < 32; i += 8)
            tile[ty + i][tx] = xp[(size_t)(d0 + ty + i) * S_ + s0 + tx];
        __syncthreads();
        bf16* xbp = xb + ((size_t)b * S_ + s0) * D_ + d0;
#pragma unroll
        for (int i = 0; i < 32; i += 8)
            xbp[(size_t)(ty + i) * D_ + tx] = (bf16)tile[tx][ty + i];
    } else {                                     // weight-pack part: 256 blocks
        const int f0 = ((bid - 4096) * 256 + threadIdx.x) * 16;  // 0..1048560
        const int src = f0 >> 18;                // 262144 elems per matrix
        const int off = f0 & 262143;
        const float* W = (src == 0) ? Wq : (src == 1) ? Wk : (src == 2) ? Wv : W0;
        float4 v0 = *(const float4*)&W[off];
        float4 v1 = *(const float4*)&W[off + 4];
        float4 v2 = *(const float4*)&W[off + 8];
        float4 v3 = *(const float4*)&W[off + 12];
        bf16x8 h0 = {(bf16)v0.x, (bf16)v0.y, (bf16)v0.z, (bf16)v0.w,
                     (bf16)v1.x, (bf16)v1.y, (bf16)v1.z, (bf16)v1.w};
        bf16x8 h1 = {(bf16)v2.x, (bf16)v2.y, (bf16)v2.z, (bf16)v2.w,
                     (bf16)v3.x, (bf16)v3.y, (bf16)v3.z, (bf16)v3.w};
        *(bf16x8*)&Wb[f0]     = h0;
        *(bf16x8*)&Wb[f0 + 8] = h1;
    }
}

// ---------------------------------------------------------------------------
// Kernel 2: fused QKV GEMM (unchanged; V stored transposed + key-swizzled:
// within each 32-key group, key 16h'+4q'+r -> stored pos 8q'+4h'+r).
// ---------------------------------------------------------------------------
__global__ __launch_bounds__(256) void gemm_qkv(
    const bf16* __restrict__ A, const bf16* __restrict__ Wb,
    const float* __restrict__ bq, const float* __restrict__ bk,
    const float* __restrict__ bv,
    bf16* __restrict__ Q, bf16* __restrict__ K, bf16* __restrict__ Vt) {
    __shared__ union {
        struct { bf16 A[8192]; bf16 B[8192]; } s;
        bf16 T[128][132];                        // epilogue transpose (33792 B)
    } sm;

    const int tid = threadIdx.x;
    const int w = tid >> 6, lane = tid & 63;
    const int m16 = lane & 15, quad = lane >> 4;
    const int wr = w & 1, wc = w >> 1;

    const int nblk = blockIdx.x % 12;            // N = 1536 / 128
    const int mblk = blockIdx.x / 12;            // M = 8192 / 128
    const int m0 = mblk * 128, n0 = nblk * 128;

    f32x4 acc[4][4];
#pragma unroll
    for (int i = 0; i < 4; ++i)
#pragma unroll
        for (int j = 0; j < 4; ++j) acc[i][j] = (f32x4){0.f, 0.f, 0.f, 0.f};

    for (int k0 = 0; k0 < D_; k0 += 64) {
        __syncthreads();
#pragma unroll
        for (int i = 0; i < 4; ++i) {            // wave w stages chunks w*4..w*4+3
            const int c  = w * 4 + i;
            const int mt = c >> 1, kk = c & 1;
            const int row = mt * 16 + m16;
            const int col = k0 + kk * 32 + quad * 8;
            GLOAD_LDS(&A[(size_t)(m0 + row) * D_ + col],  &sm.s.A[(c * 64 + lane) * 8]);
            GLOAD_LDS(&Wb[(size_t)(n0 + row) * D_ + col], &sm.s.B[(c * 64 + lane) * 8]);
        }
        __syncthreads();
#pragma unroll
        for (int kk = 0; kk < 2; ++kk) {
            bf16x8 af[4], bfv[4];
#pragma unroll
            for (int t = 0; t < 4; ++t) {
                af[t]  = *(const bf16x8*)&sm.s.A[(((wr * 4 + t) * 2 + kk) * 64 + lane) * 8];
                bfv[t] = *(const bf16x8*)&sm.s.B[(((wc * 4 + t) * 2 + kk) * 64 + lane) * 8];
            }
#pragma unroll
            for (int mt = 0; mt < 4; ++mt)
#pragma unroll
                for (int nt = 0; nt < 4; ++nt)
                    acc[mt][nt] = MFMA(af[mt], bfv[nt], acc[mt][nt]);
        }
    }

    const int proj = n0 >> 9;                    // 128-tiles never straddle
    const float* bias = (proj == 0) ? bq : (proj == 1) ? bk : bv;

    if (proj == 2) {                             // V: direct swizzled store
#pragma unroll
        for (int mt = 0; mt < 4; ++mt)
#pragma unroll
            for (int nt = 0; nt < 4; ++nt) {
                const int nr = (n0 + wc * 64 + nt * 16 + m16) & 511;
                const int h = nr >> 6, e = nr & 63;
                const float bia = bias[nr];
                const int srow = m0 + wr * 64 + mt * 16 + quad * 4;
                const int b = srow >> 11, s = srow & 2047;
                const int s2 = (s & ~31) | (quad * 8 + (mt & 1) * 4);  // key swizzle
                bf16x4 hv;
#pragma unroll
                for (int r = 0; r < 4; ++r) hv[r] = (bf16)(acc[mt][nt][r] + bia);
                *(bf16x4*)&Vt[(((size_t)b * H_ + h) * DV_ + e) * S_ + s2] = hv;
            }
    } else {                                     // Q/K: LDS transpose -> bf16x8
        __syncthreads();
#pragma unroll
        for (int mt = 0; mt < 4; ++mt)
#pragma unroll
            for (int nt = 0; nt < 4; ++nt) {
                const int nloc = wc * 64 + nt * 16 + m16;
                const float bia = bias[(n0 + nloc) & 511];
#pragma unroll
                for (int r = 0; r < 4; ++r)
                    sm.T[wr * 64 + mt * 16 + quad * 4 + r][nloc] =
                        (bf16)(acc[mt][nt][r] + bia);
            }
        __syncthreads();
        const int rloc = tid >> 1, cb = (tid & 1) * 64;
        const int M = m0 + rloc, b = M >> 11, s = M & 2047;
        const int nrb = (n0 + cb) & 511;
        const int h = nrb >> 6;
        bf16* dst = ((proj == 0) ? Q : K) + (((size_t)b * H_ + h) * S_ + s) * DV_;
#pragma unroll
        for (int u = 0; u < 8; ++u)
            *(bf16x8*)&dst[u * 8] = *(const bf16x8*)&sm.T[rloc][cb + u * 8];
    }
}

// ---------------------------------------------------------------------------
// Kernel 3: flash attention v9 — hybrid 2x2 wave split (wq = 32 q-rows,
// wk = 32 keys of each 64-key tile), fragment-linear LDS (every frag read is
// base + lane*16, m97-class), double-buffered GLOAD + raw-barrier pipeline.
//   K chunk c(=rowgrp*2+colhalf): Ks[buf][c][lane*8] = K[t0+(c>>1)*16+(l&15)]
//     [((c&1)*4+(l>>4))*8 ..+8]; reader (wk,tt,kk) uses c=(wk*2+tt)*2+kk.
//   V chunk c(=et*2+wk): Vs[buf][c][lane*8] = Vt[(c>>1)*16+(l&15)]
//     [t0+(c&1)*32+(l>>4)*8 ..+8]; Vt pre-swizzled so PV B-frag = exp'd S^T
//     C-tiles in-lane (v5 bijection).
// ---------------------------------------------------------------------------
__global__ __launch_bounds__(256, 3) void flash_attn(
    const bf16* __restrict__ Q, const bf16* __restrict__ K, const bf16* __restrict__ Vt,
    const float* __restrict__ mask, bf16* __restrict__ heads) {
    __shared__ union {
        struct {
            bf16 Ks[2][8][512];                  // [buf][chunk][lane*8] 16 KB
            bf16 Vs[2][8][512];                  // 16 KB
        } s;
        struct { float O[64][68]; float L[64]; } red;
    } sm;
    __shared__ float Ms[2048];

    const int bidx = blockIdx.x;                 // B*H*(S/64) = 1024
    const int qblk = bidx & 31;
    const int h    = (bidx >> 5) & 7;
    const int b    = bidx >> 8;
    const int q0   = qblk * 64;

    const int tid = threadIdx.x;
    const int w = tid >> 6, lane = tid & 63;
    const int m16 = lane & 15, quad = lane >> 4;
    const int wq = w & 1, wk = w >> 1;

    const bf16* Qp = Q  + ((size_t)b * H_ + h) * S_ * DV_;
    const bf16* Kp = K  + ((size_t)b * H_ + h) * S_ * DV_;
    const bf16* Vp = Vt + ((size_t)b * H_ + h) * DV_ * S_;
    const float* mp = mask + (size_t)b * S_;

    // staging source lane constants (fragment mapping)
    const int lr = lane & 15;                    // row-within-16
    const int lc = lane >> 4;                    // col sub-chunk 0..3

    // Q B-frags for this wave's 32 q-rows, pre-scaled by 1/8 (exact in bf16)
    bf16x8 qf[2][2];
#pragma unroll
    for (int qt = 0; qt < 2; ++qt)
#pragma unroll
        for (int kk = 0; kk < 2; ++kk) {
            bf16x8 v = *(const bf16x8*)&Qp[(size_t)(q0 + wq * 32 + qt * 16 + m16) * DV_ +
                                           kk * 32 + quad * 8];
#pragma unroll
            for (int i = 0; i < 8; ++i) v[i] = (bf16)((float)v[i] * 0.125f);
            qf[qt][kk] = v;
        }

    bf16x8 ones;
#pragma unroll
    for (int i = 0; i < 8; ++i) ones[i] = (bf16)1.0f;

    f32x4 o[4][2];                               // O^T[e=16et+4quad+r][q=wq*32+16qt+m16]
    f32x4 lacc[2];
#pragma unroll
    for (int et = 0; et < 4; ++et)
#pragma unroll
        for (int qt = 0; qt < 2; ++qt) o[et][qt] = (f32x4){0.f, 0.f, 0.f, 0.f};
#pragma unroll
    for (int qt = 0; qt < 2; ++qt) lacc[qt] = (f32x4){0.f, 0.f, 0.f, 0.f};

    // ---- prologue: mask (2 GLOADs/wave) + tile 0 (4 GLOADs/wave) ----
#pragma unroll
    for (int p = 0; p < 2; ++p) {
        const int mo = ((w * 2 + p) * 64 + lane) * 4;    // 16B of mask
        GLOAD_LDS(&mp[mo], &Ms[mo]);
    }
#pragma unroll
    for (int p = 0; p < 2; ++p) {
        GLOAD_LDS(&Kp[(size_t)(w * 16 + lr) * DV_ + (p * 4 + lc) * 8],
                  &sm.s.Ks[0][2 * w + p][lane * 8]);
        GLOAD_LDS(&Vp[(size_t)(w * 16 + lr) * S_ + p * 32 + lc * 8],
                  &sm.s.Vs[0][2 * w + p][lane * 8]);
    }
    __syncthreads();                             // one full drain, prologue only

    for (int i = 0; i < 32; ++i) {
        const int t0 = i * 64;
        const int buf = i & 1;
        const int tw = t0 + wk * 32;             // this wave's 32 keys

        if (i < 31) {                            // issue tile i+1 into other buf
            const int tn = t0 + 64;
            const int nb = buf ^ 1;
#pragma unroll
            for (int p = 0; p < 2; ++p) {
                GLOAD_LDS(&Kp[(size_t)(tn + w * 16 + lr) * DV_ + (p * 4 + lc) * 8],
                          &sm.s.Ks[nb][2 * w + p][lane * 8]);
                GLOAD_LDS(&Vp[(size_t)(w * 16 + lr) * S_ + tn + p * 32 + lc * 8],
                          &sm.s.Vs[nb][2 * w + p][lane * 8]);
            }
        }

        // frag loads: all lane-linear b128
        bf16x8 kf[2][2];
#pragma unroll
        for (int tt = 0; tt < 2; ++tt)
#pragma unroll
            for (int kk = 0; kk < 2; ++kk)
                kf[tt][kk] = *(const bf16x8*)&sm.s.Ks[buf][(wk * 2 + tt) * 2 + kk][lane * 8];
        bf16x8 vf[4];
#pragma unroll
        for (int et = 0; et < 4; ++et)
            vf[et] = *(const bf16x8*)&sm.s.Vs[buf][et * 2 + wk][lane * 8];
        const f32x4 mq0 = *(const f32x4*)&Ms[tw + quad * 4];
        const f32x4 mq1 = *(const f32x4*)&Ms[tw + 16 + quad * 4];

        // S^T: sc[tt][qt], lane = s[t=tw+16tt+4quad+r][q=q0+wq*32+16qt+m16]
        f32x4 sc[2][2];
#pragma unroll
        for (int tt = 0; tt < 2; ++tt)
#pragma unroll
            for (int qt = 0; qt < 2; ++qt) sc[tt][qt] = (f32x4){0.f, 0.f, 0.f, 0.f};
#pragma unroll
        for (int kk = 0; kk < 2; ++kk)
#pragma unroll
            for (int tt = 0; tt < 2; ++tt)
#pragma unroll
                for (int qt = 0; qt < 2; ++qt)
                    sc[tt][qt] = MFMA(kf[tt][kk], qf[qt][kk], sc[tt][qt]);

        // mask + exp -> PV B-frags in-lane (v5 bijection, Vt pre-swizzled)
        f32x4 ng0, ng1;
#pragma unroll
        for (int r = 0; r < 4; ++r) {
            ng0[r] = (1.0f - mq0[r]) * -1e30f;
            ng1[r] = (1.0f - mq1[r]) * -1e30f;
        }
        bf16x8 pf[2];
#pragma unroll
        for (int qt = 0; qt < 2; ++qt)
#pragma unroll
            for (int r = 0; r < 4; ++r) {
                pf[qt][r]     = (bf16)__expf(sc[0][qt][r] * mq0[r] + ng0[r]);
                pf[qt][4 + r] = (bf16)__expf(sc[1][qt][r] * mq1[r] + ng1[r]);
            }

        // PV + l (k = this wave's 32 keys)
#pragma unroll
        for (int qt = 0; qt < 2; ++qt) {
            lacc[qt] = MFMA(ones, pf[qt], lacc[qt]);
#pragma unroll
            for (int et = 0; et < 4; ++et)
                o[et][qt] = MFMA(vf[et], pf[qt], o[et][qt]);
        }

        if (i < 31) {
            WAIT_VMCNT(0);                       // covered by the compute above
            RAW_BARRIER();
        }
    }

    // ---- cross-wave reduction over wk pairs ----
    __syncthreads();
#pragma unroll
    for (int ph = 0; ph < 2; ++ph) {
        if (wk == ph) {
#pragma unroll
            for (int et = 0; et < 4; ++et)
#pragma unroll
                for (int qt = 0; qt < 2; ++qt)
#pragma unroll
                    for (int r = 0; r < 4; ++r) {
                        float* slot = &sm.red.O[et * 16 + quad * 4 + r]
                                                [wq * 32 + qt * 16 + m16];
                        *slot = (ph == 0) ? o[et][qt][r] : (*slot + o[et][qt][r]);
                    }
            if (quad == 0)
#pragma unroll
                for (int qt = 0; qt < 2; ++qt) {
                    float* ls = &sm.red.L[wq * 32 + qt * 16 + m16];
                    *ls = (ph == 0) ? lacc[qt][0] : (*ls + lacc[qt][0]);
                }
        }
        __syncthreads();
    }

    // ---- final store: thread -> (q = tid>>2, 16-wide e-chunk = (tid&3)*16) ----
    const int ql = tid >> 2, ec = (tid & 3) * 16;
    const float l  = sm.red.L[ql];
    const float qm = mp[q0 + ql];
    const float inv = qm / l;
    bf16x8 hv[2];
#pragma unroll
    for (int c = 0; c < 2; ++c)
#pragma unroll
        for (int i = 0; i < 8; ++i)
            hv[c][i] = (bf16)(sm.red.O[ec + c * 8 + i][ql] * inv);
    bf16* dst = &heads[((size_t)b * S_ + q0 + ql) * D_ + h * DV_ + ec];
    *(bf16x8*)(dst)     = hv[0];
    *(bf16x8*)(dst + 8) = hv[1];
}

// ---------------------------------------------------------------------------
// Kernel 4: out projection (unchanged this round)
// ---------------------------------------------------------------------------
__global__ __launch_bounds__(256) void gemm_out(
    const bf16* __restrict__ A, const bf16* __restrict__ Wb,
    const float* __restrict__ b0, float* __restrict__ outp) {
    __shared__ bf16 Asl[8192];
    __shared__ bf16 Bsl[8192];

    const int tid = threadIdx.x;
    const int w = tid >> 6, lane = tid & 63;
    const int m16 = lane & 15, quad = lane >> 4;
    const int wr = w & 1, wc = w >> 1;

    const int nblk = blockIdx.x & 3;             // N = 512 / 128
    const int mblk = blockIdx.x >> 2;            // M = 8192 / 128
    const int m0 = mblk * 128, n0 = nblk * 128;

    f32x4 acc[4][4];
#pragma unroll
    for (int i = 0; i < 4; ++i)
#pragma unroll
        for (int j = 0; j < 4; ++j) acc[i][j] = (f32x4){0.f, 0.f, 0.f, 0.f};

    for (int k0 = 0; k0 < D_; k0 += 64) {
        __syncthreads();
#pragma unroll
        for (int i = 0; i < 4; ++i) {
            const int c  = w * 4 + i;
            const int mt = c >> 1, kk = c & 1;
            const int row = mt * 16 + m16;
            const int col = k0 + kk * 32 + quad * 8;
            GLOAD_LDS(&A[(size_t)(m0 + row) * D_ + col], &Asl[(c * 64 + lane) * 8]);
            GLOAD_LDS(&Wb[(size_t)(1536 + n0 + row) * D_ + col], &Bsl[(c * 64 + lane) * 8]);
        }
        __syncthreads();
#pragma unroll
        for (int kk = 0; kk < 2; ++kk) {
            bf16x8 af[4], bfv[4];
#pragma unroll
            for (int t = 0; t < 4; ++t) {
                af[t]  = *(const bf16x8*)&Asl[(((wr * 4 + t) * 2 + kk) * 64 + lane) * 8];
                bfv[t] = *(const bf16x8*)&Bsl[(((wc * 4 + t) * 2 + kk) * 64 + lane) * 8];
            }
#pragma unroll
            for (int mt = 0; mt < 4; ++mt)
#pragma unroll
                for (int nt = 0; nt < 4; ++nt)
                    acc[mt][nt] = MFMA(af[mt], bfv[nt], acc[mt][nt]);
        }
    }

#pragma unroll
    for (int mt = 0; mt < 4; ++mt)
#pragma unroll
        for (int nt = 0; nt < 4; ++nt) {
            const int n = n0 + wc * 64 + nt * 16 + m16;
            const float bia = b0[n];
            const int srow = m0 + wr * 64 + mt * 16 + quad * 4;
            const int b = srow >> 11, s = srow & 2047;
            float4 vv;
            vv.x = acc[mt][nt][0] + bia;
            vv.y = acc[mt][nt][1] + bia;
            vv.z = acc[mt][nt][2] + bia;
            vv.w = acc[mt][nt][3] + bia;
            *(float4*)&outp[((size_t)b * D_ + n) * S_ + s] = vv;
        }
}

// ---------------------------------------------------------------------------
extern "C" void kernel_launch(void* const* d_in, const int* in_sizes, int n_in,
                              void* d_out, int out_size, void* d_ws, size_t ws_size,
                              hipStream_t stream) {
    const float* x    = (const float*)d_in[0];
    const float* mask = (const float*)d_in[1];
    const float* Wq   = (const float*)d_in[2];
    const float* bq   = (const float*)d_in[3];
    const float* Wk   = (const float*)d_in[4];
    const float* bk   = (const float*)d_in[5];
    const float* Wv   = (const float*)d_in[6];
    const float* bv   = (const float*)d_in[7];
    const float* W0   = (const float*)d_in[8];
    const float* b0   = (const float*)d_in[9];
    float* out = (float*)d_out;

    char* ws = (char*)d_ws;
    const size_t SEG = (size_t)B_ * S_ * D_ * sizeof(bf16);   // 8 MiB
    bf16* xb    = (bf16*)(ws);            // reused as `heads` after gemm_qkv
    bf16* Qb    = (bf16*)(ws + SEG);
    bf16* Kb    = (bf16*)(ws + 2 * SEG);
    bf16* Vt    = (bf16*)(ws + 3 * SEG);
    bf16* Wb    = (bf16*)(ws + 4 * SEG);  // 2048x512 bf16 = 2 MiB
    bf16* heads = xb;

    prep<<<dim3(4096 + 256), dim3(256), 0, stream>>>(x, Wq, Wk, Wv, W0, xb, Wb);
    gemm_qkv<<<dim3(64 * 12), dim3(256), 0, stream>>>(xb, Wb, bq, bk, bv, Qb, Kb, Vt);
    flash_attn<<<dim3(B_ * H_ * (S_ / 64)), dim3(256), 0, stream>>>(Qb, Kb, Vt, mask, heads);
    gemm_out<<<dim3(64 * 4), dim3(256), 0, stream>>>(heads, Wb, b0, out);
}

// Round 10
// 227.386 us; speedup vs baseline: 1.2545x; 1.0661x over previous
//
#include <hip/hip_runtime.h>

#define B_  4
#define D_  512
#define H_  8
#define DV_ 64
#define S_  2048
#define LOG2E 1.4426950408889634f

typedef __bf16 bf16;
typedef bf16  bf16x8 __attribute__((ext_vector_type(8)));
typedef bf16  bf16x4 __attribute__((ext_vector_type(4)));
typedef float f32x4  __attribute__((ext_vector_type(4)));

#define MFMA(a, b, c) __builtin_amdgcn_mfma_f32_16x16x32_bf16((a), (b), (c), 0, 0, 0)

// async global->LDS, 16B per lane; LDS dest is wave-uniform base + lane*16
#define GLOAD_LDS(g, l)                                                     \
    __builtin_amdgcn_global_load_lds(                                       \
        (const __attribute__((address_space(1))) void*)(g),                 \
        (__attribute__((address_space(3))) void*)(l), 16, 0, 0)

// s_waitcnt with vmcnt(n), lgkm/exp unconstrained (gfx9 encoding)
#define WAIT_VMCNT(n)                                                       \
    __builtin_amdgcn_s_waitcnt(((n) & 15) | (((n) >> 4) << 14) | (7 << 4) | (15 << 8))

// ---------------------------------------------------------------------------
// Kernel 1: prep = transpose x (B,D,S fp32 -> B,S,D bf16)  +  pack weights
// ---------------------------------------------------------------------------
__global__ __launch_bounds__(256) void prep(
    const float* __restrict__ x, const float* __restrict__ Wq,
    const float* __restrict__ Wk, const float* __restrict__ Wv,
    const float* __restrict__ W0, bf16* __restrict__ xb, bf16* __restrict__ Wb) {
    const int bid = blockIdx.x;
    if (bid < 4096) {                            // transpose part
        __shared__ float tile[32][33];
        const int sblk = bid % 64;               // S/32
        const int dblk = (bid / 64) % 16;        // D/32
        const int b    = bid / 1024;
        const int d0 = dblk * 32, s0 = sblk * 32;
        const int tx = threadIdx.x & 31;
        const int ty = threadIdx.x >> 5;         // 0..7
        const float* xp = x + (size_t)b * D_ * S_;
#pragma unroll
        for (int i = 0; i < 32; i += 8)
            tile[ty + i][tx] = xp[(size_t)(d0 + ty + i) * S_ + s0 + tx];
        __syncthreads();
        bf16* xbp = xb + ((size_t)b * S_ + s0) * D_ + d0;
#pragma unroll
        for (int i = 0; i < 32; i += 8)
            xbp[(size_t)(ty + i) * D_ + tx] = (bf16)tile[tx][ty + i];
    } else {                                     // weight-pack part: 256 blocks
        const int f0 = ((bid - 4096) * 256 + threadIdx.x) * 16;  // 0..1048560
        const int src = f0 >> 18;                // 262144 elems per matrix
        const int off = f0 & 262143;
        const float* W = (src == 0) ? Wq : (src == 1) ? Wk : (src == 2) ? Wv : W0;
        float4 v0 = *(const float4*)&W[off];
        float4 v1 = *(const float4*)&W[off + 4];
        float4 v2 = *(const float4*)&W[off + 8];
        float4 v3 = *(const float4*)&W[off + 12];
        bf16x8 h0 = {(bf16)v0.x, (bf16)v0.y, (bf16)v0.z, (bf16)v0.w,
                     (bf16)v1.x, (bf16)v1.y, (bf16)v1.z, (bf16)v1.w};
        bf16x8 h1 = {(bf16)v2.x, (bf16)v2.y, (bf16)v2.z, (bf16)v2.w,
                     (bf16)v3.x, (bf16)v3.y, (bf16)v3.z, (bf16)v3.w};
        *(bf16x8*)&Wb[f0]     = h0;
        *(bf16x8*)&Wb[f0 + 8] = h1;
    }
}

// ---------------------------------------------------------------------------
// Kernel 2: fused QKV GEMM, 64x128 tiles -> 1536 blocks (6/CU).
// Fragment-linear LDS chunks; V stored transposed + key-swizzled (within each
// 32-key group, key 16h'+4q'+r -> pos 8q'+4h'+r) for flash's PV B-frags.
// ---------------------------------------------------------------------------
__global__ __launch_bounds__(256) void gemm_qkv(
    const bf16* __restrict__ A, const bf16* __restrict__ Wb,
    const float* __restrict__ bq, const float* __restrict__ bk,
    const float* __restrict__ bv,
    bf16* __restrict__ Q, bf16* __restrict__ K, bf16* __restrict__ Vt) {
    __shared__ union {
        struct { bf16 A[4096]; bf16 B[8192]; } s;   // 8 + 16 chunks, 24 KB
        bf16 T[64][132];                             // epilogue transpose
    } sm;

    const int tid = threadIdx.x;
    const int w = tid >> 6, lane = tid & 63;
    const int m16 = lane & 15, quad = lane >> 4;
    const int lr = lane & 15, lc = lane >> 4;
    const int wr = w & 1, wc = w >> 1;

    const int nblk = blockIdx.x % 12;            // N = 1536 / 128
    const int mblk = blockIdx.x / 12;            // M = 8192 / 64
    const int m0 = mblk * 64, n0 = nblk * 128;

    f32x4 acc[2][4];
#pragma unroll
    for (int i = 0; i < 2; ++i)
#pragma unroll
        for (int j = 0; j < 4; ++j) acc[i][j] = (f32x4){0.f, 0.f, 0.f, 0.f};

    for (int k0 = 0; k0 < D_; k0 += 64) {
        __syncthreads();
#pragma unroll
        for (int j = 0; j < 2; ++j) {            // A chunks 2w, 2w+1
            const int c = 2 * w + j;
            GLOAD_LDS(&A[(size_t)(m0 + (c >> 1) * 16 + lr) * D_ + k0 + (c & 1) * 32 + lc * 8],
                      &sm.s.A[(c * 64 + lane) * 8]);
        }
#pragma unroll
        for (int j = 0; j < 4; ++j) {            // B chunks 4w..4w+3
            const int c = 4 * w + j;
            GLOAD_LDS(&Wb[(size_t)(n0 + (c >> 1) * 16 + lr) * D_ + k0 + (c & 1) * 32 + lc * 8],
                      &sm.s.B[(c * 64 + lane) * 8]);
        }
        __syncthreads();
#pragma unroll
        for (int kk = 0; kk < 2; ++kk) {
            bf16x8 af[2], bfv[4];
#pragma unroll
            for (int mt = 0; mt < 2; ++mt)
                af[mt] = *(const bf16x8*)&sm.s.A[(((wr * 2 + mt) * 2 + kk) * 64 + lane) * 8];
#pragma unroll
            for (int nt = 0; nt < 4; ++nt)
                bfv[nt] = *(const bf16x8*)&sm.s.B[(((wc * 4 + nt) * 2 + kk) * 64 + lane) * 8];
#pragma unroll
            for (int mt = 0; mt < 2; ++mt)
#pragma unroll
                for (int nt = 0; nt < 4; ++nt)
                    acc[mt][nt] = MFMA(af[mt], bfv[nt], acc[mt][nt]);
        }
    }

    const int proj = n0 >> 9;                    // 128-tiles never straddle
    const float* bias = (proj == 0) ? bq : (proj == 1) ? bk : bv;

    if (proj == 2) {                             // V: direct swizzled store
#pragma unroll
        for (int mt = 0; mt < 2; ++mt)
#pragma unroll
            for (int nt = 0; nt < 4; ++nt) {
                const int nr = (n0 + wc * 64 + nt * 16 + m16) & 511;
                const int h = nr >> 6, e = nr & 63;
                const float bia = bias[nr];
                const int srow = m0 + wr * 32 + mt * 16 + quad * 4;
                const int b = srow >> 11, s = srow & 2047;
                const int s2 = (s & ~31) | (quad * 8 + mt * 4);   // key swizzle
                bf16x4 hv;
#pragma unroll
                for (int r = 0; r < 4; ++r) hv[r] = (bf16)(acc[mt][nt][r] + bia);
                *(bf16x4*)&Vt[(((size_t)b * H_ + h) * DV_ + e) * S_ + s2] = hv;
            }
    } else {                                     // Q/K: LDS transpose -> bf16x8
        __syncthreads();
#pragma unroll
        for (int mt = 0; mt < 2; ++mt)
#pragma unroll
            for (int nt = 0; nt < 4; ++nt) {
                const int nloc = wc * 64 + nt * 16 + m16;
                const float bia = bias[(n0 + nloc) & 511];
#pragma unroll
                for (int r = 0; r < 4; ++r)
                    sm.T[wr * 32 + mt * 16 + quad * 4 + r][nloc] =
                        (bf16)(acc[mt][nt][r] + bia);
            }
        __syncthreads();
        const int rloc = tid >> 2, cb = (tid & 3) * 32;
        const int M = m0 + rloc, b = M >> 11, s = M & 2047;
        const int ncol = (n0 + cb) & 511;
        const int h = ncol >> 6, e0 = ncol & 63;
        bf16* dst = ((proj == 0) ? Q : K) + (((size_t)b * H_ + h) * S_ + s) * DV_ + e0;
#pragma unroll
        for (int u = 0; u < 4; ++u)
            *(bf16x8*)&dst[u * 8] = *(const bf16x8*)&sm.T[rloc][cb + u * 8];
    }
}

// ---------------------------------------------------------------------------
// Kernel 3: flash attention v10 = r7 structure (wave-private K/V GLOAD
// double-buffer, WAIT_VMCNT(8), no loop barriers) with:
//  - fragment-linear staging chunks (reads are pure base+lane*16)
//  - exp2f + mask premultiplied by log2e (saves one v_mul per P element)
//  - loop-carried global pointers (K: 1 ptr + imm offsets; V: 4 ptrs)
// ---------------------------------------------------------------------------
__global__ __launch_bounds__(256, 2) void flash_attn(
    const bf16* __restrict__ Q, const bf16* __restrict__ K, const bf16* __restrict__ Vt,
    const float* __restrict__ mask, bf16* __restrict__ heads) {
    __shared__ union {
        struct {
            bf16 Kl[2][4][2048];                 // [buf][wave][chunk c*512+lane*8]
            bf16 Vl[2][4][2048];
        } s;                                     // 65536 B
        struct { float O[64][65]; float L[64]; } red;
    } sm;
    __shared__ float Ms[2048];                   // mask * log2e

    const int bidx = blockIdx.x;                 // B*H*(S/64) = 1024
    const int qblk = bidx & 31;
    const int h    = (bidx >> 5) & 7;
    const int b    = bidx >> 8;
    const int q0   = qblk * 64;

    const int tid = threadIdx.x;
    const int w = tid >> 6, lane = tid & 63;
    const int m16 = lane & 15, quad = lane >> 4;
    const int lr = lane & 15, lc = lane >> 4;

    const bf16* Qp = Q  + ((size_t)b * H_ + h) * S_ * DV_;
    const bf16* Kp = K  + ((size_t)b * H_ + h) * S_ * DV_;
    const bf16* Vp = Vt + ((size_t)b * H_ + h) * DV_ * S_;
    const float* mp = mask + (size_t)b * S_;

    // loop-carried staging pointers (start at tile 0, this wave's 32 keys)
    const bf16* kgp = Kp + (size_t)(w * 32 + lr) * DV_ + lc * 8;
    const bf16* vgp0 = Vp + (size_t)(lr) * S_      + w * 32 + lc * 8;
    const bf16* vgp1 = Vp + (size_t)(16 + lr) * S_ + w * 32 + lc * 8;
    const bf16* vgp2 = Vp + (size_t)(32 + lr) * S_ + w * 32 + lc * 8;
    const bf16* vgp3 = Vp + (size_t)(48 + lr) * S_ + w * 32 + lc * 8;

    // Q B-frags for 64 q-rows, pre-scaled by 1/8 (exact in bf16)
    bf16x8 qf[4][2];
#pragma unroll
    for (int qt = 0; qt < 4; ++qt)
#pragma unroll
        for (int kk = 0; kk < 2; ++kk) {
            bf16x8 v = *(const bf16x8*)&Qp[(size_t)(q0 + qt * 16 + m16) * DV_ +
                                           kk * 32 + quad * 8];
#pragma unroll
            for (int i = 0; i < 8; ++i) v[i] = (bf16)((float)v[i] * 0.125f);
            qf[qt][kk] = v;
        }

    bf16x8 ones;
#pragma unroll
    for (int i = 0; i < 8; ++i) ones[i] = (bf16)1.0f;

    f32x4 o[4][4];                               // O^T[e=16mt+4quad+r][q=16qt+m16]
    f32x4 lacc[4];
#pragma unroll
    for (int mt = 0; mt < 4; ++mt)
#pragma unroll
        for (int qt = 0; qt < 4; ++qt) o[mt][qt] = (f32x4){0.f, 0.f, 0.f, 0.f};
#pragma unroll
    for (int qt = 0; qt < 4; ++qt) lacc[qt] = (f32x4){0.f, 0.f, 0.f, 0.f};

    // ---- prologue: mask*log2e via VALU; K/V batch 0 via GLOAD ----
    {
        const int mi = tid * 8;
        const float4 a = *(const float4*)&mp[mi];
        const float4 c = *(const float4*)&mp[mi + 4];
        Ms[mi + 0] = a.x * LOG2E; Ms[mi + 1] = a.y * LOG2E;
        Ms[mi + 2] = a.z * LOG2E; Ms[mi + 3] = a.w * LOG2E;
        Ms[mi + 4] = c.x * LOG2E; Ms[mi + 5] = c.y * LOG2E;
        Ms[mi + 6] = c.z * LOG2E; Ms[mi + 7] = c.w * LOG2E;
    }
#pragma unroll
    for (int c = 0; c < 4; ++c) {
        GLOAD_LDS(kgp + (c >> 1) * 16 * DV_ + (c & 1) * 32, &sm.s.Kl[0][w][(c * 64 + lane) * 8]);
    }
    GLOAD_LDS(vgp0, &sm.s.Vl[0][w][(0 * 64 + lane) * 8]);
    GLOAD_LDS(vgp1, &sm.s.Vl[0][w][(1 * 64 + lane) * 8]);
    GLOAD_LDS(vgp2, &sm.s.Vl[0][w][(2 * 64 + lane) * 8]);
    GLOAD_LDS(vgp3, &sm.s.Vl[0][w][(3 * 64 + lane) * 8]);
    __syncthreads();                             // Ms visible (drains prologue)

    for (int i = 0; i < 16; ++i) {
        const int tw = i * 128 + w * 32;         // this wave's 32 keys
        const int buf = i & 1;

        if (i < 15) {                            // issue batch i+1 -> other buf
            kgp  += 128 * DV_;
            vgp0 += 128; vgp1 += 128; vgp2 += 128; vgp3 += 128;
            const int nb = buf ^ 1;
#pragma unroll
            for (int c = 0; c < 4; ++c)
                GLOAD_LDS(kgp + (c >> 1) * 16 * DV_ + (c & 1) * 32,
                          &sm.s.Kl[nb][w][(c * 64 + lane) * 8]);
            GLOAD_LDS(vgp0, &sm.s.Vl[nb][w][(0 * 64 + lane) * 8]);
            GLOAD_LDS(vgp1, &sm.s.Vl[nb][w][(1 * 64 + lane) * 8]);
            GLOAD_LDS(vgp2, &sm.s.Vl[nb][w][(2 * 64 + lane) * 8]);
            GLOAD_LDS(vgp3, &sm.s.Vl[nb][w][(3 * 64 + lane) * 8]);
            WAIT_VMCNT(8);                       // batch i complete
        } else {
            WAIT_VMCNT(0);
        }

        // frag loads: all lane-linear b128
        bf16x8 kf[2][2];
#pragma unroll
        for (int tt = 0; tt < 2; ++tt)
#pragma unroll
            for (int kk = 0; kk < 2; ++kk)
                kf[tt][kk] = *(const bf16x8*)&sm.s.Kl[buf][w][((tt * 2 + kk) * 64 + lane) * 8];
        bf16x8 vf[4];
#pragma unroll
        for (int mt = 0; mt < 4; ++mt)
            vf[mt] = *(const bf16x8*)&sm.s.Vl[buf][w][(mt * 64 + lane) * 8];
        const f32x4 mq0 = *(const f32x4*)&Ms[tw + quad * 4];
        const f32x4 mq1 = *(const f32x4*)&Ms[tw + 16 + quad * 4];

        // S^T: sc[tt][qt], lane = s[t=tw+16tt+4quad+r][q=q0+16qt+m16]
        f32x4 sc[2][4];
#pragma unroll
        for (int tt = 0; tt < 2; ++tt)
#pragma unroll
            for (int qt = 0; qt < 4; ++qt) sc[tt][qt] = (f32x4){0.f, 0.f, 0.f, 0.f};
#pragma unroll
        for (int kk = 0; kk < 2; ++kk)
#pragma unroll
            for (int tt = 0; tt < 2; ++tt)
#pragma unroll
                for (int qt = 0; qt < 4; ++qt)
                    sc[tt][qt] = MFMA(kf[tt][kk], qf[qt][kk], sc[tt][qt]);

        // mask + exp2 -> PV B-frags in-lane (Vt pre-swizzled bijection)
        f32x4 ng0, ng1;
#pragma unroll
        for (int r = 0; r < 4; ++r) {
            ng0[r] = (LOG2E - mq0[r]) * -7e29f;
            ng1[r] = (LOG2E - mq1[r]) * -7e29f;
        }
        bf16x8 pf[4];
#pragma unroll
        for (int qt = 0; qt < 4; ++qt)
#pragma unroll
            for (int r = 0; r < 4; ++r) {
                pf[qt][r]     = (bf16)exp2f(sc[0][qt][r] * mq0[r] + ng0[r]);
                pf[qt][4 + r] = (bf16)exp2f(sc[1][qt][r] * mq1[r] + ng1[r]);
            }

        // PV + l
#pragma unroll
        for (int mt = 0; mt < 4; ++mt)
#pragma unroll
            for (int qt = 0; qt < 4; ++qt) o[mt][qt] = MFMA(vf[mt], pf[qt], o[mt][qt]);
#pragma unroll
        for (int qt = 0; qt < 4; ++qt) lacc[qt] = MFMA(ones, pf[qt], lacc[qt]);
    }

    // ---- cross-wave reduction (turn-based accumulate into red) ----
    __syncthreads();
#pragma unroll
    for (int ww = 0; ww < 4; ++ww) {
        if (w == ww) {
#pragma unroll
            for (int mt = 0; mt < 4; ++mt)
#pragma unroll
                for (int qt = 0; qt < 4; ++qt)
#pragma unroll
                    for (int r = 0; r < 4; ++r) {
                        float* slot = &sm.red.O[mt * 16 + quad * 4 + r][qt * 16 + m16];
                        *slot = (ww == 0) ? o[mt][qt][r] : (*slot + o[mt][qt][r]);
                    }
            if (quad == 0)
#pragma unroll
                for (int qt = 0; qt < 4; ++qt) {
                    float* ls = &sm.red.L[qt * 16 + m16];
                    *ls = (ww == 0) ? lacc[qt][0] : (*ls + lacc[qt][0]);
                }
        }
        __syncthreads();
    }

    // ---- final store: thread -> (q = tid>>2, 16-wide e-chunk = (tid&3)*16) ----
    const int ql = tid >> 2, ec = (tid & 3) * 16;
    const float l  = sm.red.L[ql];
    const float qm = mp[q0 + ql];
    const float inv = qm / l;
    bf16x8 hv[2];
#pragma unroll
    for (int c = 0; c < 2; ++c)
#pragma unroll
        for (int i = 0; i < 8; ++i)
            hv[c][i] = (bf16)(sm.red.O[ec + c * 8 + i][ql] * inv);
    bf16* dst = &heads[((size_t)b * S_ + q0 + ql) * D_ + h * DV_ + ec];
    *(bf16x8*)(dst)     = hv[0];
    *(bf16x8*)(dst + 8) = hv[1];
}

// ---------------------------------------------------------------------------
// Kernel 4: out projection, 64x128 tiles -> 512 blocks (2/CU).
// ---------------------------------------------------------------------------
__global__ __launch_bounds__(256) void gemm_out(
    const bf16* __restrict__ A, const bf16* __restrict__ Wb,
    const float* __restrict__ b0, float* __restrict__ outp) {
    __shared__ bf16 Asl[4096];
    __shared__ bf16 Bsl[8192];

    const int tid = threadIdx.x;
    const int w = tid >> 6, lane = tid & 63;
    const int m16 = lane & 15, quad = lane >> 4;
    const int lr = lane & 15, lc = lane >> 4;
    const int wr = w & 1, wc = w >> 1;

    const int nblk = blockIdx.x & 3;             // N = 512 / 128
    const int mblk = blockIdx.x >> 2;            // M = 8192 / 64
    const int m0 = mblk * 64, n0 = nblk * 128;

    f32x4 acc[2][4];
#pragma unroll
    for (int i = 0; i < 2; ++i)
#pragma unroll
        for (int j = 0; j < 4; ++j) acc[i][j] = (f32x4){0.f, 0.f, 0.f, 0.f};

    for (int k0 = 0; k0 < D_; k0 += 64) {
        __syncthreads();
#pragma unroll
        for (int j = 0; j < 2; ++j) {
            const int c = 2 * w + j;
            GLOAD_LDS(&A[(size_t)(m0 + (c >> 1) * 16 + lr) * D_ + k0 + (c & 1) * 32 + lc * 8],
                      &Asl[(c * 64 + lane) * 8]);
        }
#pragma unroll
        for (int j = 0; j < 4; ++j) {
            const int c = 4 * w + j;
            GLOAD_LDS(&Wb[(size_t)(1536 + n0 + (c >> 1) * 16 + lr) * D_ + k0 + (c & 1) * 32 + lc * 8],
                      &Bsl[(c * 64 + lane) * 8]);
        }
        __syncthreads();
#pragma unroll
        for (int kk = 0; kk < 2; ++kk) {
            bf16x8 af[2], bfv[4];
#pragma unroll
            for (int mt = 0; mt < 2; ++mt)
                af[mt] = *(const bf16x8*)&Asl[(((wr * 2 + mt) * 2 + kk) * 64 + lane) * 8];
#pragma unroll
            for (int nt = 0; nt < 4; ++nt)
                bfv[nt] = *(const bf16x8*)&Bsl[(((wc * 4 + nt) * 2 + kk) * 64 + lane) * 8];
#pragma unroll
            for (int mt = 0; mt < 2; ++mt)
#pragma unroll
                for (int nt = 0; nt < 4; ++nt)
                    acc[mt][nt] = MFMA(af[mt], bfv[nt], acc[mt][nt]);
        }
    }

#pragma unroll
    for (int mt = 0; mt < 2; ++mt)
#pragma unroll
        for (int nt = 0; nt < 4; ++nt) {
            const int n = n0 + wc * 64 + nt * 16 + m16;
            const float bia = b0[n];
            const int srow = m0 + wr * 32 + mt * 16 + quad * 4;
            const int b = srow >> 11, s = srow & 2047;
            float4 vv;
            vv.x = acc[mt][nt][0] + bia;
            vv.y = acc[mt][nt][1] + bia;
            vv.z = acc[mt][nt][2] + bia;
            vv.w = acc[mt][nt][3] + bia;
            *(float4*)&outp[((size_t)b * D_ + n) * S_ + s] = vv;
        }
}

// ---------------------------------------------------------------------------
extern "C" void kernel_launch(void* const* d_in, const int* in_sizes, int n_in,
                              void* d_out, int out_size, void* d_ws, size_t ws_size,
                              hipStream_t stream) {
    const float* x    = (const float*)d_in[0];
    const float* mask = (const float*)d_in[1];
    const float* Wq   = (const float*)d_in[2];
    const float* bq   = (const float*)d_in[3];
    const float* Wk   = (const float*)d_in[4];
    const float* bk   = (const float*)d_in[5];
    const float* Wv   = (const float*)d_in[6];
    const float* bv   = (const float*)d_in[7];
    const float* W0   = (const float*)d_in[8];
    const float* b0   = (const float*)d_in[9];
    float* out = (float*)d_out;

    char* ws = (char*)d_ws;
    const size_t SEG = (size_t)B_ * S_ * D_ * sizeof(bf16);   // 8 MiB
    bf16* xb    = (bf16*)(ws);            // reused as `heads` after gemm_qkv
    bf16* Qb    = (bf16*)(ws + SEG);
    bf16* Kb    = (bf16*)(ws + 2 * SEG);
    bf16* Vt    = (bf16*)(ws + 3 * SEG);
    bf16* Wb    = (bf16*)(ws + 4 * SEG);  // 2048x512 bf16 = 2 MiB
    bf16* heads = xb;

    prep<<<dim3(4096 + 256), dim3(256), 0, stream>>>(x, Wq, Wk, Wv, W0, xb, Wb);
    gemm_qkv<<<dim3(128 * 12), dim3(256), 0, stream>>>(xb, Wb, bq, bk, bv, Qb, Kb, Vt);
    flash_attn<<<dim3(B_ * H_ * (S_ / 64)), dim3(256), 0, stream>>>(Qb, Kb, Vt, mask, heads);
    gemm_out<<<dim3(128 * 4), dim3(256), 0, stream>>>(heads, Wb, b0, out);
}